// Round 4
// baseline (374.399 us; speedup 1.0000x reference)
//
#include <hip/hip_runtime.h>

#define NN 50000      // nodes
#define NE 800000     // edges
#define FIN 512
#define H1DIM 64
#define H2DIM 128
#define NC 10
#define NG 64

typedef __attribute__((ext_vector_type(8))) short bf16x8;  // 8 bf16 (4 VGPRs)
typedef __attribute__((ext_vector_type(4))) float f32x4;

__device__ inline short f2bf(float f) {
  unsigned u = __float_as_uint(f);
  unsigned r = u + 0x7fffu + ((u >> 16) & 1u);  // RNE
  return (short)(r >> 16);
}
__device__ inline float bf2f(short s) {
  return __uint_as_float(((unsigned)(unsigned short)s) << 16);
}

// ---------------------------------------------------------------------------
// wbt[n][k] = bf16( n<64 ? w1l[k][n] : w1r[k][n-64] )   [128][512] bf16
// ---------------------------------------------------------------------------
__global__ __launch_bounds__(256) void wbt_prep_kernel(
    const float* __restrict__ wl, const float* __restrict__ wr,
    short* __restrict__ wbt) {
  int idx = blockIdx.x * 256 + threadIdx.x;   // 0..65535
  int n = idx >> 9;        // 0..127
  int k = idx & 511;       // 0..511
  float v = (n < 64) ? wl[(size_t)k * 64 + n] : wr[(size_t)k * 64 + (n - 64)];
  wbt[idx] = f2bf(v);
}

// ---------------------------------------------------------------------------
// GEMM1 (MFMA bf16): [50000,512] @ [512,128] -> xwl(bf16), xwr(f32)
// block tile 64x128, K-step 32, 4 waves, wave 32x64.
// Double-buffered LDS + register prefetch: one barrier per K-step, global
// load latency overlapped with MFMA of the current step.
// ---------------------------------------------------------------------------
__global__ __launch_bounds__(256) void gemm1_mfma_kernel(
    const float* __restrict__ x, const short* __restrict__ wbt,
    short* __restrict__ xwl, float* __restrict__ xwr) {
  __shared__ short Asl[2][64][40];    // [buf][m][k], stride 40 shorts (80 B)
  __shared__ short Bsl[2][128][40];   // [buf][n][k]

  const int tid = threadIdx.x;
  const int wave = tid >> 6;
  const int lane = tid & 63;
  const int l15 = lane & 15;
  const int q = lane >> 4;             // 0..3
  const int mw = (wave & 1) * 32;
  const int nw = (wave >> 1) * 64;
  const int m0 = blockIdx.x * 64;

  const f32x4 z = {0.f, 0.f, 0.f, 0.f};
  f32x4 acc[2][4];
#pragma unroll
  for (int mi = 0; mi < 2; mi++)
#pragma unroll
    for (int ni = 0; ni < 4; ni++) acc[mi][ni] = z;

  const int ar = tid >> 2;             // 0..63
  const int ac = (tid & 3) * 8;        // 0,8,16,24
  const int agm = m0 + ar;
  const bool arow_ok = (agm < NN);
  const int bn = tid >> 1;             // 0..127
  const int bc = (tid & 1) * 16;       // 0,16

  // ---- prologue: load tile 0 into regs, stage to buf 0 ----
  float4 av0 = make_float4(0.f, 0.f, 0.f, 0.f);
  float4 av1 = make_float4(0.f, 0.f, 0.f, 0.f);
  if (arow_ok) {
    const float* p = x + (size_t)agm * FIN + ac;
    av0 = *(const float4*)(p);
    av1 = *(const float4*)(p + 4);
  }
  const short* bp0 = wbt + (size_t)bn * FIN + bc;
  bf16x8 bv0 = *(const bf16x8*)(bp0);
  bf16x8 bv1 = *(const bf16x8*)(bp0 + 8);
  {
    bf16x8 apack;
    apack[0] = f2bf(av0.x); apack[1] = f2bf(av0.y);
    apack[2] = f2bf(av0.z); apack[3] = f2bf(av0.w);
    apack[4] = f2bf(av1.x); apack[5] = f2bf(av1.y);
    apack[6] = f2bf(av1.z); apack[7] = f2bf(av1.w);
    *(bf16x8*)(&Asl[0][ar][ac]) = apack;
    *(bf16x8*)(&Bsl[0][bn][bc]) = bv0;
    *(bf16x8*)(&Bsl[0][bn][bc + 8]) = bv1;
  }
  __syncthreads();

  for (int ks = 0; ks < 16; ks++) {
    const int cur = ks & 1;
    const int nxt = cur ^ 1;
    // issue next-tile loads first (latency overlapped with frags+MFMA below)
    float4 nv0, nv1;
    bf16x8 nb0, nb1;
    if (ks < 15) {
      int k0 = (ks + 1) * 32;
      if (arow_ok) {
        const float* p = x + (size_t)agm * FIN + k0 + ac;
        nv0 = *(const float4*)(p);
        nv1 = *(const float4*)(p + 4);
      }
      const short* bp = wbt + (size_t)bn * FIN + k0 + bc;
      nb0 = *(const bf16x8*)(bp);
      nb1 = *(const bf16x8*)(bp + 8);
    }

    bf16x8 afrag[2], bfrag[4];
#pragma unroll
    for (int mi = 0; mi < 2; mi++)
      afrag[mi] = *(const bf16x8*)(&Asl[cur][mw + mi * 16 + l15][q * 8]);
#pragma unroll
    for (int ni = 0; ni < 4; ni++)
      bfrag[ni] = *(const bf16x8*)(&Bsl[cur][nw + ni * 16 + l15][q * 8]);
#pragma unroll
    for (int mi = 0; mi < 2; mi++)
#pragma unroll
      for (int ni = 0; ni < 4; ni++)
        acc[mi][ni] = __builtin_amdgcn_mfma_f32_16x16x32_bf16(
            afrag[mi], bfrag[ni], acc[mi][ni], 0, 0, 0);

    if (ks < 15) {
      bf16x8 apack;
      if (!arow_ok) { nv0 = make_float4(0.f,0.f,0.f,0.f); nv1 = nv0; }
      apack[0] = f2bf(nv0.x); apack[1] = f2bf(nv0.y);
      apack[2] = f2bf(nv0.z); apack[3] = f2bf(nv0.w);
      apack[4] = f2bf(nv1.x); apack[5] = f2bf(nv1.y);
      apack[6] = f2bf(nv1.z); apack[7] = f2bf(nv1.w);
      *(bf16x8*)(&Asl[nxt][ar][ac]) = apack;
      *(bf16x8*)(&Bsl[nxt][bn][bc]) = nb0;
      *(bf16x8*)(&Bsl[nxt][bn][bc + 8]) = nb1;
      __syncthreads();
    }
  }

  // epilogue: C[row][col], col = nw+ni*16+l15; row = m0+mw+mi*16+q*4+r
#pragma unroll
  for (int mi = 0; mi < 2; mi++) {
    int row_base = m0 + mw + mi * 16 + q * 4;
#pragma unroll
    for (int ni = 0; ni < 4; ni++) {
      int col = nw + ni * 16 + l15;
      int c = col & 63;
#pragma unroll
      for (int r = 0; r < 4; r++) {
        int row = row_base + r;
        if (row < NN) {
          if (col < 64) xwl[(size_t)row * 64 + c] = f2bf(acc[mi][ni][r]);
          else          xwr[(size_t)row * 64 + c] = acc[mi][ni][r];
        }
      }
    }
  }
}

// ---------------------------------------------------------------------------
// counting sort: hist -> multi-block scan -> scatter  (int4 edge reads)
// ---------------------------------------------------------------------------
__global__ __launch_bounds__(256) void hist_kernel(const int* __restrict__ dst,
                                                   int* __restrict__ cnt) {
  int i = (blockIdx.x * 256 + threadIdx.x) * 4;
  if (i < NE) {
    int4 d = *(const int4*)(dst + i);
    atomicAdd(&cnt[d.x], 1);
    atomicAdd(&cnt[d.y], 1);
    atomicAdd(&cnt[d.z], 1);
    atomicAdd(&cnt[d.w], 1);
  }
}

#define SCAN_BLOCKS 196   // ceil(50000/256)

__global__ __launch_bounds__(256) void scan1_kernel(const int* __restrict__ cnt,
                                                    int* __restrict__ excl,
                                                    int* __restrict__ bsum) {
  __shared__ int s[256];
  int t = threadIdx.x;
  int i = blockIdx.x * 256 + t;
  int v = (i < NN) ? cnt[i] : 0;
  s[t] = v;
  __syncthreads();
  for (int off = 1; off < 256; off <<= 1) {
    int u = (t >= off) ? s[t - off] : 0;
    __syncthreads();
    s[t] += u;
    __syncthreads();
  }
  if (i < NN) excl[i] = s[t] - v;       // exclusive within block
  if (t == 255) bsum[blockIdx.x] = s[255];
}

__global__ __launch_bounds__(256) void scan2_kernel(int* __restrict__ bsum) {
  __shared__ int s[256];
  int t = threadIdx.x;
  int v = (t < SCAN_BLOCKS) ? bsum[t] : 0;
  s[t] = v;
  __syncthreads();
  for (int off = 1; off < 256; off <<= 1) {
    int u = (t >= off) ? s[t - off] : 0;
    __syncthreads();
    s[t] += u;
    __syncthreads();
  }
  bsum[t] = s[t] - v;                    // exclusive block offsets
}

__global__ __launch_bounds__(256) void scan3_kernel(const int* __restrict__ bsum,
                                                    int* __restrict__ rowptr,
                                                    int* __restrict__ cursor) {
  int t = threadIdx.x;
  int i = blockIdx.x * 256 + t;
  if (i < NN) {
    int p = rowptr[i] + bsum[blockIdx.x];
    rowptr[i] = p;
    cursor[i] = p;
  }
  if (i == 0) rowptr[NN] = NE;
}

__global__ __launch_bounds__(256) void scatter_kernel(
    const int* __restrict__ src, const int* __restrict__ dst,
    int* __restrict__ cursor, int* __restrict__ ssrc) {
  int i = (blockIdx.x * 256 + threadIdx.x) * 4;
  if (i < NE) {
    int4 s = *(const int4*)(src + i);
    int4 d = *(const int4*)(dst + i);
    int p0 = atomicAdd(&cursor[d.x], 1); ssrc[p0] = s.x;
    int p1 = atomicAdd(&cursor[d.y], 1); ssrc[p1] = s.y;
    int p2 = atomicAdd(&cursor[d.z], 1); ssrc[p2] = s.z;
    int p3 = atomicAdd(&cursor[d.w], 1); ssrc[p3] = s.w;
  }
}

// ---------------------------------------------------------------------------
// agg1 + h1 fused: h1 = relu(mean_{s in N(i)} xwl[s] + b1 + xwr[i])  (bf16 out)
// one wave per node; 8 chunk-lanes x 8 edge-slots, 16B gathers
// ---------------------------------------------------------------------------
__global__ __launch_bounds__(256) void agg1_h1_kernel(
    const int* __restrict__ rowptr, const int* __restrict__ ssrc,
    const short* __restrict__ xwl, const float* __restrict__ xwr,
    const float* __restrict__ b1, short* __restrict__ h1) {
  int node = blockIdx.x * 4 + (threadIdx.x >> 6);
  if (node >= NN) return;
  int lane = threadIdx.x & 63;
  int c = lane & 7;        // feature chunk (8 bf16 = 16 B)
  int r = lane >> 3;       // edge slot 0..7
  int lo = rowptr[node], hi = rowptr[node + 1];
  float acc[8];
#pragma unroll
  for (int k = 0; k < 8; k++) acc[k] = 0.f;
  for (int e = lo + r; e < hi; e += 8) {
    int s = ssrc[e];
    bf16x8 v = *(const bf16x8*)(xwl + (size_t)s * 64 + c * 8);
#pragma unroll
    for (int k = 0; k < 8; k++) acc[k] += bf2f(v[k]);
  }
#pragma unroll
  for (int k = 0; k < 8; k++) {
    acc[k] += __shfl_xor(acc[k], 8);
    acc[k] += __shfl_xor(acc[k], 16);
    acc[k] += __shfl_xor(acc[k], 32);
  }
  if (r == 0) {
    float dg = fmaxf((float)(hi - lo), 1.0f);
    const float* xr = xwr + (size_t)node * 64 + c * 8;
    bf16x8 out;
#pragma unroll
    for (int k = 0; k < 8; k++) {
      float v = acc[k] / dg + b1[c * 8 + k] + xr[k];
      out[k] = f2bf(fmaxf(v, 0.f));
    }
    *(bf16x8*)(h1 + (size_t)node * 64 + c * 8) = out;
  }
}

// ---------------------------------------------------------------------------
// agg2: agg2[i] = sum_{s in N(i)} h1[s]   (f32 out)
// ---------------------------------------------------------------------------
__global__ __launch_bounds__(256) void agg2_kernel(
    const int* __restrict__ rowptr, const int* __restrict__ ssrc,
    const short* __restrict__ h1, float* __restrict__ agg2) {
  int node = blockIdx.x * 4 + (threadIdx.x >> 6);
  if (node >= NN) return;
  int lane = threadIdx.x & 63;
  int c = lane & 7;
  int r = lane >> 3;
  int lo = rowptr[node], hi = rowptr[node + 1];
  float acc[8];
#pragma unroll
  for (int k = 0; k < 8; k++) acc[k] = 0.f;
  for (int e = lo + r; e < hi; e += 8) {
    int s = ssrc[e];
    bf16x8 v = *(const bf16x8*)(h1 + (size_t)s * 64 + c * 8);
#pragma unroll
    for (int k = 0; k < 8; k++) acc[k] += bf2f(v[k]);
  }
#pragma unroll
  for (int k = 0; k < 8; k++) {
    acc[k] += __shfl_xor(acc[k], 8);
    acc[k] += __shfl_xor(acc[k], 16);
    acc[k] += __shfl_xor(acc[k], 32);
  }
  if (r == 0) {
    float* p = agg2 + (size_t)node * 64 + c * 8;
    f32x4 lo4 = {acc[0], acc[1], acc[2], acc[3]};
    f32x4 hi4 = {acc[4], acc[5], acc[6], acc[7]};
    *(f32x4*)(p) = lo4;
    *(f32x4*)(p + 4) = hi4;
  }
}

// ---------------------------------------------------------------------------
// pool phase1: run-length accumulate (batch sorted) + atomic flush
// ---------------------------------------------------------------------------
__global__ __launch_bounds__(256) void pool1_kernel(
    const int* __restrict__ batch, const float* __restrict__ agg2,
    const short* __restrict__ h1, const int* __restrict__ rowptr,
    float* __restrict__ poolA, float* __restrict__ poolB,
    float* __restrict__ poolCnt) {
  int t = threadIdx.x;
  int c = t & 15;
  int s = t >> 4;
  int n0 = blockIdx.x * 256 + s * 16;
  int n1 = n0 + 16;
  if (n1 > NN) n1 = NN;

  f32x4 aA = {0.f, 0.f, 0.f, 0.f};
  f32x4 aB = {0.f, 0.f, 0.f, 0.f};
  int cur_g = -1;
  float run = 0.f;
  for (int n = n0; n < n1; n++) {
    int g = batch[n];
    if (g != cur_g) {
      if (cur_g >= 0) {
        float* pa = poolA + (size_t)cur_g * 64 + c * 4;
        float* pb = poolB + (size_t)cur_g * 64 + c * 4;
#pragma unroll
        for (int k = 0; k < 4; k++) {
          atomicAdd(&pa[k], aA[k]);
          atomicAdd(&pb[k], aB[k]);
        }
        if (c == 0) atomicAdd(&poolCnt[cur_g], run);
      }
      cur_g = g;
      aA = (f32x4){0.f, 0.f, 0.f, 0.f};
      aB = (f32x4){0.f, 0.f, 0.f, 0.f};
      run = 0.f;
    }
    float rd = 1.0f / fmaxf((float)(rowptr[n + 1] - rowptr[n]), 1.0f);
    f32x4 a2 = *(const f32x4*)(agg2 + (size_t)n * 64 + c * 4);
    const short* hp = h1 + (size_t)n * 64 + c * 4;
#pragma unroll
    for (int k = 0; k < 4; k++) {
      aA[k] = fmaf(a2[k], rd, aA[k]);
      aB[k] += bf2f(hp[k]);
    }
    run += 1.f;
  }
  if (cur_g >= 0) {
    float* pa = poolA + (size_t)cur_g * 64 + c * 4;
    float* pb = poolB + (size_t)cur_g * 64 + c * 4;
#pragma unroll
    for (int k = 0; k < 4; k++) {
      atomicAdd(&pa[k], aA[k]);
      atomicAdd(&pb[k], aB[k]);
    }
    if (c == 0) atomicAdd(&poolCnt[cur_g], run);
  }
}

// ---------------------------------------------------------------------------
// final: pooled = (poolA/cnt)@w2l + (poolB/cnt)@w2r + b2 ; @wfc + bfc ;
// log_softmax. One block per graph.
// ---------------------------------------------------------------------------
__global__ __launch_bounds__(128) void final_kernel(
    const float* __restrict__ poolA, const float* __restrict__ poolB,
    const float* __restrict__ poolCnt, const float* __restrict__ w2l,
    const float* __restrict__ w2r, const float* __restrict__ b2,
    const float* __restrict__ wfc, const float* __restrict__ bfc,
    float* __restrict__ out) {
  int g = blockIdx.x;
  int j = threadIdx.x;
  __shared__ float sp[H2DIM];
  __shared__ float sl[NC];

  float invc = 1.0f / fmaxf(poolCnt[g], 1.0f);
  float v = b2[j];
  for (int k = 0; k < 64; k++) {
    float a = poolA[g * 64 + k] * invc;
    float b = poolB[g * 64 + k] * invc;
    v = fmaf(a, w2l[k * 128 + j], v);
    v = fmaf(b, w2r[k * 128 + j], v);
  }
  sp[j] = v;
  __syncthreads();
  if (j < NC) {
    float lg = bfc[j];
    for (int k = 0; k < H2DIM; k++) lg = fmaf(sp[k], wfc[k * NC + j], lg);
    sl[j] = lg;
  }
  __syncthreads();
  if (j < NC) {
    float m = -1e30f;
    for (int k = 0; k < NC; k++) m = fmaxf(m, sl[k]);
    float s = 0.f;
    for (int k = 0; k < NC; k++) s += expf(sl[k] - m);
    out[g * NC + j] = sl[j] - m - logf(s);
  }
}

extern "C" void kernel_launch(void* const* d_in, const int* in_sizes, int n_in,
                              void* d_out, int out_size, void* d_ws,
                              size_t ws_size, hipStream_t stream) {
  const float* x   = (const float*)d_in[0];
  const int* edge  = (const int*)d_in[1];
  const int* batch = (const int*)d_in[2];
  const float* w1l = (const float*)d_in[3];
  const float* b1l = (const float*)d_in[4];
  const float* w1r = (const float*)d_in[5];
  const float* w2l = (const float*)d_in[6];
  const float* b2l = (const float*)d_in[7];
  const float* w2r = (const float*)d_in[8];
  const float* wfc = (const float*)d_in[9];
  const float* bfc = (const float*)d_in[10];
  float* out = (float*)d_out;

  const int* src = edge;
  const int* dst = edge + NE;

  const size_t NF = (size_t)NN * 64;
  // zero region: cnt[NN] + poolA[4096] + poolB[4096] + poolCnt[64]
  int*   cnt     = (int*)d_ws;
  float* poolA   = (float*)(cnt + NN);
  float* poolB   = poolA + (size_t)NG * 64;
  float* poolCnt = poolB + (size_t)NG * 64;
  int*   cursor  = (int*)(poolCnt + NG);
  int*   rowptr  = cursor + NN;            // [NN+1] padded to 50004
  int*   ssrc    = rowptr + 50004;
  int*   bsum    = ssrc + NE;              // [256]
  short* xwl     = (short*)(bsum + 256);   // bf16 [NN][64]
  short* h1s     = xwl + NF;               // bf16 [NN][64]
  float* xwr     = (float*)(h1s + NF);     // f32  [NN][64]
  float* agg2    = xwr + NF;               // f32  [NN][64]
  short* wbt     = (short*)(agg2 + NF);    // bf16 [128][512]

  hipMemsetAsync(cnt, 0, (NN + 2 * NG * 64 + NG) * sizeof(int), stream);

  hist_kernel<<<(NE / 4 + 255) / 256, 256, 0, stream>>>(dst, cnt);
  scan1_kernel<<<SCAN_BLOCKS, 256, 0, stream>>>(cnt, rowptr, bsum);
  scan2_kernel<<<1, 256, 0, stream>>>(bsum);
  scan3_kernel<<<SCAN_BLOCKS, 256, 0, stream>>>(bsum, rowptr, cursor);
  scatter_kernel<<<(NE / 4 + 255) / 256, 256, 0, stream>>>(src, dst, cursor, ssrc);

  wbt_prep_kernel<<<65536 / 256, 256, 0, stream>>>(w1l, w1r, wbt);
  gemm1_mfma_kernel<<<(NN + 63) / 64, 256, 0, stream>>>(x, wbt, xwl, xwr);

  agg1_h1_kernel<<<(NN + 3) / 4, 256, 0, stream>>>(rowptr, ssrc, xwl, xwr, b1l, h1s);
  agg2_kernel<<<(NN + 3) / 4, 256, 0, stream>>>(rowptr, ssrc, h1s, agg2);
  pool1_kernel<<<SCAN_BLOCKS, 256, 0, stream>>>(batch, agg2, h1s, rowptr, poolA, poolB, poolCnt);
  final_kernel<<<NG, 128, 0, stream>>>(poolA, poolB, poolCnt, w2l, w2r, b2l, wfc, bfc, out);
}